// Round 1
// 741.329 us; speedup vs baseline: 1.1018x; 1.1018x over previous
//
#include <hip/hip_runtime.h>

#define B 32
#define L 2048
#define H 1024
#define K2 2048            // 2*H
#define NL 8               // l-values per wave in scores kernel
#define HSPLIT 32
#define HCHUNK (H / HSPLIT)  // 32

typedef float f4 __attribute__((ext_vector_type(4)));

// ---------------------------------------------------------------------------
// v[b,h] = sum_g hs[b,g] * attn_W[g,h]        (32 x 1024)
// grid: 128 blocks x 256 thr; b uniform per block -> hs reads are s_loads.
// 4 rotating accumulators + unroll 4 => 16 loads in flight (was 1 serial chain).
// ---------------------------------------------------------------------------
__global__ __launch_bounds__(256) void v_kernel(const float* __restrict__ hs,
                                                const float* __restrict__ attn_W,
                                                float* __restrict__ v) {
    int tid = blockIdx.x * 256 + threadIdx.x;   // 0..32767
    int b = tid >> 10;
    int h = tid & (H - 1);
    const float* hsb = hs + b * H;
    float a0 = 0.f, a1 = 0.f, a2 = 0.f, a3 = 0.f;
    #pragma unroll 4
    for (int g = 0; g < H; g += 4) {
        a0 = fmaf(hsb[g + 0], attn_W[(g + 0) * H + h], a0);  // coalesced
        a1 = fmaf(hsb[g + 1], attn_W[(g + 1) * H + h], a1);
        a2 = fmaf(hsb[g + 2], attn_W[(g + 2) * H + h], a2);
        a3 = fmaf(hsb[g + 3], attn_W[(g + 3) * H + h], a3);
    }
    v[tid] = (a0 + a1) + (a2 + a3);
}

// ---------------------------------------------------------------------------
// pw[s][b][k] = sum_{h in chunk s} v[b,h] * reduce_W[h,k]
// grid: (K2/512, HSPLIT) = (4,32) = 128 blocks x 256 thr; float2 over k.
// v reads are wave-uniform -> scalar-load path. acc[32] float2 = 64 VGPR.
// ---------------------------------------------------------------------------
__global__ __launch_bounds__(256) void w_partial_kernel(const float* __restrict__ v,
                                                        const float* __restrict__ rW,
                                                        float* __restrict__ pw) {
    int k2 = blockIdx.x * 256 + threadIdx.x;    // float2 column, 0..1023
    int h0 = blockIdx.y * HCHUNK;
    const float2* rW2 = (const float2*)rW;
    float2 acc[B];
    #pragma unroll
    for (int b = 0; b < B; ++b) { acc[b].x = 0.f; acc[b].y = 0.f; }
    for (int h = h0; h < h0 + HCHUNK; ++h) {
        float2 rw = rW2[h * (K2 / 2) + k2];     // coalesced
        #pragma unroll
        for (int b = 0; b < B; ++b) {
            float vb = v[b * H + h];            // uniform -> s_load
            acc[b].x = fmaf(vb, rw.x, acc[b].x);
            acc[b].y = fmaf(vb, rw.y, acc[b].y);
        }
    }
    float2* pw2 = (float2*)pw;
    #pragma unroll
    for (int b = 0; b < B; ++b)
        pw2[(blockIdx.y * B + b) * (K2 / 2) + k2] = acc[b];
}

// w[b,k] = sum_s pw[s][b][k]   -- grid 256 blocks
__global__ __launch_bounds__(256) void w_reduce_kernel(const float* __restrict__ pw,
                                                       float* __restrict__ w) {
    int i = blockIdx.x * 256 + threadIdx.x;     // 0..65535  (= b*K2 + k)
    float s = 0.f;
    #pragma unroll
    for (int p = 0; p < HSPLIT; ++p) s += pw[p * (B * K2) + i];
    w[i] = s;
}

// ---------------------------------------------------------------------------
// scores[b,l] = w[b,:] . enc[l,b,:]   -- THE streaming kernel (512 MB read)
// w[b] preloaded into 32 VGPRs per wave; each enc row (8 KB) is then streamed
// SEQUENTIALLY (8 consecutive 1KB wave-loads) instead of interleaving 8 rows
// at 1KB granularity -> sequential DRAM page access per wave. Non-temporal
// loads keep the 512MB stream from evicting w/scores in L2.
// grid: 2048 blocks x 256 thr (4 waves/block); block's 4 waves cover
// consecutive b => 4 adjacent 8KB rows in flight = 32KB contiguous footprint.
// ---------------------------------------------------------------------------
__global__ __launch_bounds__(256) void scores_kernel(const f4* __restrict__ enc,
                                                     const f4* __restrict__ w,
                                                     float* __restrict__ scores) {
    int wid  = blockIdx.x * 4 + (threadIdx.x >> 6);
    int lane = threadIdx.x & 63;
    int b  = wid & (B - 1);
    int l0 = (wid >> 5) * NL;
    const f4* wb = w + b * (K2 / 4) + lane;     // 8KB, L2-resident
    f4 wr[8];
    #pragma unroll
    for (int j = 0; j < 8; ++j) wr[j] = wb[j * 64];
    float acc[NL];
    #pragma unroll 2
    for (int i = 0; i < NL; ++i) {              // 2 rows in flight (16 loads)
        const f4* row = enc + ((size_t)(l0 + i) * B + b) * (K2 / 4) + lane;
        float a0 = 0.f, a1 = 0.f, a2 = 0.f, a3 = 0.f;
        #pragma unroll
        for (int j = 0; j < 8; j += 2) {        // sequential 1KB chunks of one row
            f4 ea = __builtin_nontemporal_load(row + (j + 0) * 64);
            f4 eb = __builtin_nontemporal_load(row + (j + 1) * 64);
            a0 = fmaf(wr[j].x, ea.x, a0);
            a1 = fmaf(wr[j].y, ea.y, a1);
            a2 = fmaf(wr[j].z, ea.z, a2);
            a3 = fmaf(wr[j].w, ea.w, a3);
            a0 = fmaf(wr[j + 1].x, eb.x, a0);
            a1 = fmaf(wr[j + 1].y, eb.y, a1);
            a2 = fmaf(wr[j + 1].z, eb.z, a2);
            a3 = fmaf(wr[j + 1].w, eb.w, a3);
        }
        acc[i] = (a0 + a1) + (a2 + a3);
    }
    #pragma unroll
    for (int i = 0; i < NL; ++i) {
        float s = acc[i];
        #pragma unroll
        for (int off = 32; off > 0; off >>= 1) s += __shfl_down(s, off, 64);
        if (lane == 0) scores[b * L + l0 + i] = s;
    }
}

// ---------------------------------------------------------------------------
// In-place row softmax over l (row length L=2048), one block per b.
// ---------------------------------------------------------------------------
__global__ __launch_bounds__(256) void softmax_kernel(float* __restrict__ out) {
    int b = blockIdx.x;
    int t = threadIdx.x;
    float* row = out + b * L;
    float vals[8];
    float m = -3.4e38f;
    #pragma unroll
    for (int i = 0; i < 8; ++i) { vals[i] = row[t + i * 256]; m = fmaxf(m, vals[i]); }
    __shared__ float wred[4];
    int wv = t >> 6, lane = t & 63;
    #pragma unroll
    for (int off = 1; off < 64; off <<= 1) m = fmaxf(m, __shfl_xor(m, off, 64));
    if (lane == 0) wred[wv] = m;
    __syncthreads();
    m = fmaxf(fmaxf(wred[0], wred[1]), fmaxf(wred[2], wred[3]));
    __syncthreads();                     // wred reused for the sum
    float s = 0.f;
    #pragma unroll
    for (int i = 0; i < 8; ++i) { vals[i] = __expf(vals[i] - m); s += vals[i]; }
    #pragma unroll
    for (int off = 1; off < 64; off <<= 1) s += __shfl_xor(s, off, 64);
    if (lane == 0) wred[wv] = s;
    __syncthreads();
    s = wred[0] + wred[1] + wred[2] + wred[3];
    float inv = 1.f / s;
    #pragma unroll
    for (int i = 0; i < 8; ++i) row[t + i * 256] = vals[i] * inv;
}

extern "C" void kernel_launch(void* const* d_in, const int* in_sizes, int n_in,
                              void* d_out, int out_size, void* d_ws, size_t ws_size,
                              hipStream_t stream) {
    const float* hs  = (const float*)d_in[0];   // (B,H)
    const float* enc = (const float*)d_in[1];   // (L,B,2H)
    const float* rW  = (const float*)d_in[2];   // (H,2H)
    // d_in[3] = reduce_b : cancels in softmax (constant per b)
    const float* aW  = (const float*)d_in[4];   // (H,H)
    // d_in[5] = attn_b  : cancels in softmax (constant per b)
    float* out = (float*)d_out;                 // (B,L) fp32

    char* ws = (char*)d_ws;
    float* v  = (float*)(ws);                           // B*H      = 128 KB
    float* w  = (float*)(ws + 131072);                  // B*K2     = 256 KB
    float* pw = (float*)(ws + 131072 + 262144);         // HSPLIT*B*K2 = 8 MB

    v_kernel<<<(B * H) / 256, 256, 0, stream>>>(hs, aW, v);

    dim3 g2(K2 / 512, HSPLIT);                          // (4,32)
    w_partial_kernel<<<g2, 256, 0, stream>>>(v, rW, pw);
    w_reduce_kernel<<<(B * K2) / 256, 256, 0, stream>>>(pw, w);

    scores_kernel<<<(L / NL) * B / 4, 256, 0, stream>>>((const f4*)enc,
                                                        (const f4*)w, out);
    softmax_kernel<<<B, 256, 0, stream>>>(out);
}